// Round 1
// baseline (18.758 us; speedup 1.0000x reference)
//
#include <hip/hip_runtime.h>

namespace {

constexpr int B_ = 4, C_ = 64, H_ = 96, W_ = 192, S_ = 12;
constexpr int HW = H_ * W_;
constexpr float TEMP_OVER_C = 7.0f / 64.0f;   // TEMPERATURE / C  (mean then *7)
constexpr int OUT_HALF = B_ * 4 * H_ * W_;    // 294912: ndisp_out first, then disp_out

__global__ __launch_bounds__(192) void fused_eval(
    const float* __restrict__ left, const float* __restrict__ right,
    const float* __restrict__ disp, const float* __restrict__ ndisp,
    float* __restrict__ out)
{
  __shared__ float rlds[C_ * W_];   // 49152 B, layout [c][w], no pad (idx-gather spreads banks)
  const int blk = blockIdx.x;       // b*H + h
  const int b = blk / H_;
  const int h = blk - b * H_;
  const int t = threadIdx.x;        // 0..191

  // ---- stage right[b,:,h,:] into LDS via float4 ----
  const float* rrow = right + (size_t)b * C_ * HW + (size_t)h * W_;
  #pragma unroll
  for (int j = 0; j < 16; ++j) {
    const int q  = j * 192 + t;        // float4 index, 0..3071
    const int c  = q / 48;             // 48 float4 per channel row
    const int w4 = q - c * 48;
    const float4 v = *reinterpret_cast<const float4*>(rrow + (size_t)c * HW + 4 * w4);
    *reinterpret_cast<float4*>(&rlds[c * W_ + 4 * w4]) = v;
  }

  // ---- per-thread setup (overlap with staging latency) ----
  const int w = t;
  float dsp[S_]; int idx[S_]; float st[S_];
  #pragma unroll
  for (int s = 0; s < S_; ++s) {
    dsp[s] = disp[((size_t)(b * S_ + s) * H_ + h) * W_ + w];
    // reference: clip(w - d, 0, W-1) in f32, then int32 truncation (== floor, non-negative)
    float ry = fminf(fmaxf((float)w - dsp[s], 0.0f), (float)(W_ - 1));
    idx[s] = (int)ry;
    st[s] = 0.0f;
  }

  const float* lcol = left + (size_t)b * C_ * HW + (size_t)h * W_ + w;

  __syncthreads();

  // ---- dot over channels: chunked left preload (16 regs) + LDS gathers ----
  #pragma unroll
  for (int c0 = 0; c0 < C_; c0 += 16) {
    float lreg[16];
    #pragma unroll
    for (int cc = 0; cc < 16; ++cc)
      lreg[cc] = lcol[(size_t)(c0 + cc) * HW];
    #pragma unroll
    for (int cc = 0; cc < 16; ++cc) {
      const float lc = lreg[cc];
      const float* rc = &rlds[(c0 + cc) * W_];
      #pragma unroll
      for (int s = 0; s < S_; ++s)
        st[s] = fmaf(lc, rc[idx[s]], st[s]);
    }
  }

  // ---- per-interval softmax over 3 filter taps, weighted sums ----
  float* out_d = out + OUT_HALF;
  #pragma unroll
  for (int i = 0; i < 4; ++i) {
    const float s0 = st[3*i+0] * TEMP_OVER_C;
    const float s1 = st[3*i+1] * TEMP_OVER_C;
    const float s2 = st[3*i+2] * TEMP_OVER_C;
    const float m  = fmaxf(s0, fmaxf(s1, s2));
    const float e0 = __expf(s0 - m);
    const float e1 = __expf(s1 - m);
    const float e2 = __expf(s2 - m);
    const float inv = 1.0f / (e0 + e1 + e2);
    const float w0 = e0 * inv, w1 = e1 * inv, w2 = e2 * inv;
    const float n0 = ndisp[((size_t)(b * S_ + 3*i+0) * H_ + h) * W_ + w];
    const float n1 = ndisp[((size_t)(b * S_ + 3*i+1) * H_ + h) * W_ + w];
    const float n2 = ndisp[((size_t)(b * S_ + 3*i+2) * H_ + h) * W_ + w];
    const size_t o = ((size_t)(b * 4 + i) * H_ + h) * W_ + w;
    out[o]   = n0 * w0 + n1 * w1 + n2 * w2;                                  // ndisp_out
    out_d[o] = dsp[3*i+0] * w0 + dsp[3*i+1] * w1 + dsp[3*i+2] * w2;          // disp_out
  }
}

} // namespace

extern "C" void kernel_launch(void* const* d_in, const int* in_sizes, int n_in,
                              void* d_out, int out_size, void* d_ws, size_t ws_size,
                              hipStream_t stream) {
  const float* left  = (const float*)d_in[0];
  const float* right = (const float*)d_in[1];
  const float* disp  = (const float*)d_in[2];
  const float* ndisp = (const float*)d_in[3];
  float* out = (float*)d_out;
  dim3 grid(B_ * H_);
  dim3 block(192);
  hipLaunchKernelGGL(fused_eval, grid, block, 0, stream, left, right, disp, ndisp, out);
}